// Round 6
// baseline (208.690 us; speedup 1.0000x reference)
//
#include <hip/hip_runtime.h>
#include <stdint.h>
#include <math.h>

#define C_NUM 2048
#define N_TOT 4096
#define B_TOT 4096
#define KNOWN 1024

typedef __attribute__((ext_vector_type(8))) short short8;
typedef __attribute__((ext_vector_type(4))) float f32x4;

__device__ __forceinline__ unsigned short f2bf(float x) {
  unsigned u = __float_as_uint(x);
  unsigned r = (u + 0x7fffu + ((u >> 16) & 1u)) >> 16;
  return (unsigned short)r;
}

__device__ __forceinline__ void gld16(const void* g, void* l) {
  __builtin_amdgcn_global_load_lds(
      (const __attribute__((address_space(1))) void*)g,
      (__attribute__((address_space(3))) void*)l, 16, 0, 0);
}

// ---- Kernel 1: transpose + bf16 convert + colsum/norm2 partials ----------
__global__ void transpose_stats_kernel(const float* __restrict__ prob,
                                       const float* __restrict__ prob_s,
                                       float* __restrict__ colsum,
                                       float* __restrict__ norm2,
                                       unsigned short* __restrict__ Pn) {
  __shared__ float tile[64][65];
  int tx = threadIdx.x;          // 0..63
  int ty = threadIdx.y;          // 0..3
  int c0 = blockIdx.x * 64;      // class tile (0..4095)
  int b0 = blockIdx.y * 64;      // batch tile
  const float* src = (c0 < C_NUM) ? prob : prob_s;
  int colbase = (c0 & (C_NUM - 1)) + tx;
  float s = 0.f, s2 = 0.f;
#pragma unroll
  for (int r = 0; r < 16; ++r) {
    int b = b0 + r * 4 + ty;
    float v = src[(size_t)b * C_NUM + colbase];
    tile[r * 4 + ty][tx] = v;
    s += v;
    s2 += v * v;
  }
  atomicAdd(&colsum[c0 + tx], s);
  atomicAdd(&norm2[c0 + tx], s2);
  __syncthreads();
#pragma unroll
  for (int r = 0; r < 16; ++r) {
    int i = c0 + r * 4 + ty;
    Pn[(size_t)i * B_TOT + b0 + tx] = f2bf(tile[tx][r * 4 + ty]);
  }
}

// ---- Kernel 2: invn[i] = 1/max(||P_i||, eps) ------------------------------
__global__ void invnorm_kernel(const float* __restrict__ norm2,
                               float* __restrict__ invn) {
  int i = blockIdx.x * 256 + threadIdx.x;
  invn[i] = 1.0f / fmaxf(sqrtf(norm2[i]), 1e-8f);
}

// ---- Kernel 3: symmetric fused GEMM + softmax-denominator epilogue -------
// Triangular tile pairs (jt >= it), 128x128 tile. 1024 threads = 16 waves:
// waves 0-7 (group 0) accumulate K in [0,2048), waves 8-15 (group 1) K in
// [2048,4096). Each group: 2x4 wave grid, per-wave 64x32 (acc[4][2]), own
// 32 KB double-buffered LDS staged via global_load_lds with the verified
// granule swizzle (phys = (klog + row>>1) & 3, pre-permuted global source,
// linear LDS dest) -> 0 bank conflicts. After the K-loop group 1 spills its
// acc to the retired staging LDS; group 0 combines and runs the epilogue.
__global__ __launch_bounds__(1024, 8) void simgemm_kernel(
    const unsigned short* __restrict__ Pn,
    const float* __restrict__ invn,
    float* __restrict__ sumexp,
    float* __restrict__ pos) {
  __shared__ __align__(16) char lds[65536];

  const int tid = threadIdx.x;       // 0..1023
  const int l = tid & 63;
  const int w = tid >> 6;            // wave 0..15
  const int g = w >> 3;              // K-half group
  const int wv = w & 7;              // wave within group
  const int wr = wv >> 2, wc = wv & 3; // 2x4 wave grid
  const int ti = tid & 511;          // thread within group

  // triangular decode: block t -> (it, jt) with jt >= it, 32x32 tile grid
  int t = blockIdx.x;
  int it = 0, rem = 32;
  while (t >= rem) { t -= rem; ++it; --rem; }
  const int jt = it + t;
  const int ib = it * 128;
  const int jb = jt * 128;
  const bool diag = (it == jt);

  // group LDS region: A dbuf at gbase+{0,8192}, B dbuf at gbase+16384+{0,8192}
  char* const gbase = lds + g * 32768;

  // staging: ti fills linear LDS offset ti*16 (row=ti>>2, phys granule=ti&3)
  // logical granule = (phys - row>>1) & 3 -> pre-permuted global source
  const int srow = ti >> 2;
  const int glog = ((ti & 3) - (ti >> 3)) & 3;
  // group g covers K columns [g*2048, g*2048+2048): byte offset g*4096
  const char* gA = (const char*)Pn + (size_t)(ib + srow) * (B_TOT * 2) + g * 4096 + glog * 16;
  const char* gB = (const char*)Pn + (size_t)(jb + srow) * (B_TOT * 2) + g * 4096 + glog * 16;
  const int ldsOf = ti * 16;

  f32x4 acc[4][2];
#pragma unroll
  for (int a = 0; a < 4; ++a)
#pragma unroll
    for (int b = 0; b < 2; ++b)
      acc[a][b] = (f32x4){0.f, 0.f, 0.f, 0.f};

  // fragment read geometry: row stride 64B (BK=32), swizzled 16B granules
  const int arow = wr * 64 + (l & 15);
  const int brow = wc * 32 + (l & 15);
  const int klog = l >> 4;
  const int agran = (klog + (arow >> 1)) & 3;  // frag row offsets are mult of 16 -> same gran
  const int bgran = (klog + (brow >> 1)) & 3;

#define STAGE(buf, koff)                                        \
  do {                                                          \
    gld16(gA + (koff), gbase + (buf) * 8192 + ldsOf);           \
    gld16(gB + (koff), gbase + 16384 + (buf) * 8192 + ldsOf);   \
  } while (0)

  STAGE(0, 0);
  __syncthreads();

  int cur = 0;
  const int NT = 2048 / 32;   // 64 K-tiles per group
  for (int kt = 0; kt < NT; ++kt) {
    if (kt + 1 < NT) STAGE(cur ^ 1, (size_t)(kt + 1) * 64);

    const char* Abase = gbase + cur * 8192;
    const char* Bbase = gbase + 16384 + cur * 8192;

    short8 af[4], bf[2];
#pragma unroll
    for (int f = 0; f < 4; ++f)
      af[f] = *(const short8*)(Abase + (arow + f * 16) * 64 + agran * 16);
#pragma unroll
    for (int f = 0; f < 2; ++f)
      bf[f] = *(const short8*)(Bbase + (brow + f * 16) * 64 + bgran * 16);

#pragma unroll
    for (int fm = 0; fm < 4; ++fm)
#pragma unroll
      for (int fn = 0; fn < 2; ++fn)
        acc[fm][fn] = __builtin_amdgcn_mfma_f32_16x16x32_bf16(
            af[fm], bf[fn], acc[fm][fn], 0, 0, 0);

    __syncthreads();   // staging of next + reads of cur drained
    cur ^= 1;
  }
#undef STAGE

  // ---- combine: group 1 spills acc to LDS; group 0 adds ----
  // layout: wave wv at wv*8192, fragment q=fm*2+fn at q*1024, lane at l*16
  // (16B-stride f32x4: conflict-free write/read pattern)
  if (g == 1) {
#pragma unroll
    for (int fm = 0; fm < 4; ++fm)
#pragma unroll
      for (int fn = 0; fn < 2; ++fn)
        *(f32x4*)(lds + wv * 8192 + (fm * 2 + fn) * 1024 + l * 16) = acc[fm][fn];
  }
  __syncthreads();
  if (g == 1) return;

#pragma unroll
  for (int fm = 0; fm < 4; ++fm)
#pragma unroll
    for (int fn = 0; fn < 2; ++fn)
      acc[fm][fn] += *(const f32x4*)(lds + wv * 8192 + (fm * 2 + fn) * 1024 + l * 16);

  // ---- epilogue (group 0 only): v = 2 * dot * invn[i] * invn[j] ----
  float invj[2];
#pragma unroll
  for (int fn = 0; fn < 2; ++fn)
    invj[fn] = invn[jb + wc * 32 + fn * 16 + (l & 15)];

  if (diag) {
#pragma unroll
    for (int fm = 0; fm < 4; ++fm) {
#pragma unroll
      for (int r = 0; r < 4; ++r) {
        const int i = ib + wr * 64 + fm * 16 + (l >> 4) * 4 + r;
        const float invi = invn[i];
        float rs = 0.f;
#pragma unroll
        for (int fn = 0; fn < 2; ++fn) {
          const int j = jb + wc * 32 + fn * 16 + (l & 15);
          float v = acc[fm][fn][r] * 2.0f * invi * invj[fn];
          if (j != i)   // i^2048 can't occur inside a diagonal block
            rs += (((i & 1024) == 0) && (j < KNOWN)) ? 1.0f : __expf(v);
        }
        rs += __shfl_xor(rs, 1);
        rs += __shfl_xor(rs, 2);
        rs += __shfl_xor(rs, 4);
        rs += __shfl_xor(rs, 8);
        if ((l & 15) == 0) atomicAdd(&sumexp[i], rs);
      }
    }
  } else {
    float cs[2] = {0.f, 0.f};   // per-fn contribution to column rows j
#pragma unroll
    for (int fm = 0; fm < 4; ++fm) {
#pragma unroll
      for (int r = 0; r < 4; ++r) {
        const int i = ib + wr * 64 + fm * 16 + (l >> 4) * 4 + r;
        const float invi = invn[i];
        float rs = 0.f;
#pragma unroll
        for (int fn = 0; fn < 2; ++fn) {
          const int j = jb + wc * 32 + fn * 16 + (l & 15);
          float v = acc[fm][fn][r] * 2.0f * invi * invj[fn];
          if (j == (i ^ 2048)) {
            pos[i] = v;          // symmetric entry has the same value
            pos[j] = v;
          } else {               // j != i always holds off-diagonal
            float e = __expf(v);
            rs += (((i & 1024) == 0) && (j < KNOWN)) ? 1.0f : e;
            cs[fn] += (((j & 1024) == 0) && (i < KNOWN)) ? 1.0f : e;
          }
        }
        rs += __shfl_xor(rs, 1);
        rs += __shfl_xor(rs, 2);
        rs += __shfl_xor(rs, 4);
        rs += __shfl_xor(rs, 8);
        if ((l & 15) == 0) atomicAdd(&sumexp[i], rs);
      }
    }
#pragma unroll
    for (int fn = 0; fn < 2; ++fn) {
      cs[fn] += __shfl_xor(cs[fn], 16);
      cs[fn] += __shfl_xor(cs[fn], 32);
    }
    if (l < 16) {
#pragma unroll
      for (int fn = 0; fn < 2; ++fn)
        atomicAdd(&sumexp[jb + wc * 32 + fn * 16 + l], cs[fn]);
    }
  }
}

// ---- Kernel 4: finalize ---------------------------------------------------
__device__ float block_reduce_256(float v, volatile float* red) {
#pragma unroll
  for (int m = 32; m >= 1; m >>= 1) v += __shfl_xor(v, m);
  __syncthreads();
  if ((threadIdx.x & 63) == 0) red[threadIdx.x >> 6] = v;
  __syncthreads();
  return red[0] + red[1] + red[2] + red[3];
}

__global__ void finalize_kernel(const float* __restrict__ colsum,
                                const float* __restrict__ sumexp,
                                const float* __restrict__ pos,
                                float* __restrict__ out) {
  __shared__ float red[4];
  int t = threadIdx.x;
  float ce = 0.f, t1 = 0.f, t2 = 0.f;
  for (int i = t; i < N_TOT; i += 256) ce += logf(sumexp[i]) - pos[i];
  for (int c = t; c < C_NUM; c += 256) t1 += colsum[c];
  for (int c = t; c < C_NUM; c += 256) t2 += colsum[C_NUM + c];
  ce = block_reduce_256(ce, red);
  t1 = block_reduce_256(t1, red);
  t2 = block_reduce_256(t2, red);
  float e1 = 0.f, e2 = 0.f;
  for (int c = t; c < C_NUM; c += 256) {
    float m = colsum[c] / t1;
    e1 += m * logf(m);
  }
  for (int c = t; c < C_NUM; c += 256) {
    float m = colsum[C_NUM + c] / t2;
    e2 += m * logf(m);
  }
  e1 = block_reduce_256(e1, red);
  e2 = block_reduce_256(e2, red);
  if (t == 0) {
    float reg = logf((float)C_NUM) + e1 + logf((float)C_NUM) + e2;
    out[0] = ce / (float)N_TOT + reg;
  }
}

extern "C" void kernel_launch(void* const* d_in, const int* in_sizes, int n_in,
                              void* d_out, int out_size, void* d_ws, size_t ws_size,
                              hipStream_t stream) {
  const float* prob = (const float*)d_in[0];
  const float* prob_s = (const float*)d_in[1];
  float* out = (float*)d_out;

  char* ws = (char*)d_ws;
  unsigned short* Pn = (unsigned short*)ws;                     // 32 MB bf16
  float* norm2 = (float*)(ws + (size_t)N_TOT * B_TOT * 2);      // 4096 f32
  float* colsum = norm2 + N_TOT;                                // 4096 f32
  float* sumexp = colsum + N_TOT;                               // 4096 f32
  float* invn = sumexp + N_TOT;                                 // 4096 f32
  float* pos = invn + N_TOT;                                    // 4096 f32

  // zero the atomic accumulators (norm2, colsum, sumexp contiguous)
  hipMemsetAsync(norm2, 0, (size_t)3 * N_TOT * sizeof(float), stream);

  transpose_stats_kernel<<<dim3(64, 64), dim3(64, 4), 0, stream>>>(
      prob, prob_s, colsum, norm2, Pn);
  invnorm_kernel<<<16, 256, 0, stream>>>(norm2, invn);
  simgemm_kernel<<<528, 1024, 0, stream>>>(Pn, invn, sumexp, pos);
  finalize_kernel<<<1, 256, 0, stream>>>(colsum, sumexp, pos, out);
}

// Round 7
// 140.814 us; speedup vs baseline: 1.4820x; 1.4820x over previous
//
#include <hip/hip_runtime.h>
#include <hip/hip_fp8.h>
#include <stdint.h>
#include <math.h>

#define C_NUM 2048
#define N_TOT 4096
#define B_TOT 4096
#define KNOWN 1024

typedef __attribute__((ext_vector_type(4))) float f32x4;

__device__ __forceinline__ void gld16(const void* g, void* l) {
  __builtin_amdgcn_global_load_lds(
      (const __attribute__((address_space(1))) void*)g,
      (__attribute__((address_space(3))) void*)l, 16, 0, 0);
}

// ---- Kernel 1: transpose + fp8(e4m3) convert + colsum/norm2 partials -----
// Pn[i][b] = fp8(P[i][b]) UNNORMALIZED (values in [0,1)); exact f32 norms
// are applied in the GEMM epilogue.
__global__ void transpose_stats_kernel(const float* __restrict__ prob,
                                       const float* __restrict__ prob_s,
                                       float* __restrict__ colsum,
                                       float* __restrict__ norm2,
                                       uint8_t* __restrict__ Pn) {
  __shared__ float tile[64][65];
  int tx = threadIdx.x;          // 0..63
  int ty = threadIdx.y;          // 0..3
  int c0 = blockIdx.x * 64;      // class tile (0..4095)
  int b0 = blockIdx.y * 64;      // batch tile
  const float* src = (c0 < C_NUM) ? prob : prob_s;
  int colbase = (c0 & (C_NUM - 1)) + tx;
  float s = 0.f, s2 = 0.f;
#pragma unroll
  for (int r = 0; r < 16; ++r) {
    int b = b0 + r * 4 + ty;
    float v = src[(size_t)b * C_NUM + colbase];
    tile[r * 4 + ty][tx] = v;
    s += v;
    s2 += v * v;
  }
  atomicAdd(&colsum[c0 + tx], s);
  atomicAdd(&norm2[c0 + tx], s2);
  __syncthreads();
#pragma unroll
  for (int r = 0; r < 16; ++r) {
    int i = c0 + r * 4 + ty;
    __hip_fp8_e4m3 q(tile[tx][r * 4 + ty]);
    Pn[(size_t)i * B_TOT + b0 + tx] = q.__x;
  }
}

// ---- Kernel 2: invn[i] = 1/max(||P_i||, eps) ------------------------------
__global__ void invnorm_kernel(const float* __restrict__ norm2,
                               float* __restrict__ invn) {
  int i = blockIdx.x * 256 + threadIdx.x;
  invn[i] = 1.0f / fmaxf(sqrtf(norm2[i]), 1e-8f);
}

// ---- Kernel 3: symmetric fused fp8 GEMM + softmax-denom epilogue ---------
// Triangular tile pairs (jt >= it), 128x128 tile, 512 threads = 8 waves
// (2x4); per-wave 64x32 output (acc[4][2] of 16x16x32 fp8_fp8 MFMA).
// BK=32 (32 bytes/row), double-buffered 16 KB LDS. Waves 0-3 stage A,
// waves 4-7 stage B (1 gld16/thread/K-step). 16B-granule XOR swizzle
// (byte ^= ((row>>2)&1)<<4) applied on the pre-permuted global source
// (LDS dest stays linear) and on the b64 fragment reads: <=2-way banks.
__global__ __launch_bounds__(512) void simgemm_kernel(
    const uint8_t* __restrict__ Pn,
    const float* __restrict__ invn,
    float* __restrict__ sumexp,
    float* __restrict__ pos) {
  __shared__ __align__(16) char lds[16384];  // buf b: A at b*8192, B at +4096

  const int tid = threadIdx.x;
  const int l = tid & 63;
  const int w = tid >> 6;            // wave 0..7
  const int wr = w >> 2, wc = w & 3; // 2x4 wave grid

  // triangular decode: block t -> (it, jt) with jt >= it, 32x32 tile grid
  int t = blockIdx.x;
  int it = 0, rem = 32;
  while (t >= rem) { t -= rem; ++it; --rem; }
  const int jt = it + t;
  const int ib = it * 128;
  const int jb = jt * 128;
  const bool diag = (it == jt);

  // staging: s = tid&255 covers 16B; row = s>>1 (0..127), phys granule s&1.
  // logical 16B granule = (s&1) ^ ((row>>2)&1)  -> pre-permuted global col.
  const int s = tid & 255;
  const int srow = s >> 1;
  const int glog = (s & 1) ^ ((s >> 3) & 1);
  const int pbase = (w < 4) ? ib : jb;
  const char* gsrc = (const char*)Pn + (size_t)(pbase + srow) * B_TOT + glog * 16;
  const int ldsWr = ((w < 4) ? 0 : 4096) + s * 16;

  f32x4 acc[4][2];
#pragma unroll
  for (int a = 0; a < 4; ++a)
#pragma unroll
    for (int b = 0; b < 2; ++b)
      acc[a][b] = (f32x4){0.f, 0.f, 0.f, 0.f};

  // fragment read geometry: rows of 32B, b64 at koct*8 with XOR swizzle
  const int arow = wr * 64 + (l & 15);
  const int brow = wc * 32 + (l & 15);
  const int koct = (l >> 4) * 8;                  // byte offset of k-octet
  const int xorA = ((arow >> 2) & 1) << 4;        // f*16 rows keep bit2
  const int xorB = ((brow >> 2) & 1) << 4;

#define STAGE(buf, koff) gld16(gsrc + (koff), lds + (buf) * 8192 + ldsWr)

  STAGE(0, 0);
  __syncthreads();

  int cur = 0;
  const int NT = B_TOT / 32;   // 128 K-tiles (32 bytes each)
  for (int kt = 0; kt < NT; ++kt) {
    if (kt + 1 < NT) STAGE(cur ^ 1, (kt + 1) * 32);

    const char* Abase = lds + cur * 8192;
    const char* Bbase = Abase + 4096;

    long long af[4], bf[2];
#pragma unroll
    for (int f = 0; f < 4; ++f)
      af[f] = *(const long long*)(Abase + (arow + f * 16) * 32 + (koct ^ xorA));
#pragma unroll
    for (int f = 0; f < 2; ++f)
      bf[f] = *(const long long*)(Bbase + (brow + f * 16) * 32 + (koct ^ xorB));

#pragma unroll
    for (int fm = 0; fm < 4; ++fm)
#pragma unroll
      for (int fn = 0; fn < 2; ++fn)
        acc[fm][fn] = __builtin_amdgcn_mfma_f32_16x16x32_fp8_fp8(
            af[fm], bf[fn], acc[fm][fn], 0, 0, 0);

    __syncthreads();   // drains staging of next + reads of cur
    cur ^= 1;
  }
#undef STAGE

  // epilogue. v = 2 * dot * invn[i] * invn[j]
  float invj[2];
#pragma unroll
  for (int fn = 0; fn < 2; ++fn)
    invj[fn] = invn[jb + wc * 32 + fn * 16 + (l & 15)];

  if (diag) {
#pragma unroll
    for (int fm = 0; fm < 4; ++fm) {
#pragma unroll
      for (int r = 0; r < 4; ++r) {
        const int i = ib + wr * 64 + fm * 16 + (l >> 4) * 4 + r;
        const float invi = invn[i];
        float rs = 0.f;
#pragma unroll
        for (int fn = 0; fn < 2; ++fn) {
          const int j = jb + wc * 32 + fn * 16 + (l & 15);
          float v = acc[fm][fn][r] * 2.0f * invi * invj[fn];
          if (j != i)   // i^2048 can't occur inside a diagonal block
            rs += (((i & 1024) == 0) && (j < KNOWN)) ? 1.0f : __expf(v);
        }
        rs += __shfl_xor(rs, 1);
        rs += __shfl_xor(rs, 2);
        rs += __shfl_xor(rs, 4);
        rs += __shfl_xor(rs, 8);
        if ((l & 15) == 0) atomicAdd(&sumexp[i], rs);
      }
    }
  } else {
    float cs[2] = {0.f, 0.f};   // per-fn contribution to column rows j
#pragma unroll
    for (int fm = 0; fm < 4; ++fm) {
#pragma unroll
      for (int r = 0; r < 4; ++r) {
        const int i = ib + wr * 64 + fm * 16 + (l >> 4) * 4 + r;
        const float invi = invn[i];
        float rs = 0.f;
#pragma unroll
        for (int fn = 0; fn < 2; ++fn) {
          const int j = jb + wc * 32 + fn * 16 + (l & 15);
          float v = acc[fm][fn][r] * 2.0f * invi * invj[fn];
          if (j == (i ^ 2048)) {
            pos[i] = v;          // symmetric entry has the same value
            pos[j] = v;
          } else {               // j != i always holds off-diagonal
            float e = __expf(v);
            rs += (((i & 1024) == 0) && (j < KNOWN)) ? 1.0f : e;
            cs[fn] += (((j & 1024) == 0) && (i < KNOWN)) ? 1.0f : e;
          }
        }
        rs += __shfl_xor(rs, 1);
        rs += __shfl_xor(rs, 2);
        rs += __shfl_xor(rs, 4);
        rs += __shfl_xor(rs, 8);
        if ((l & 15) == 0) atomicAdd(&sumexp[i], rs);
      }
    }
#pragma unroll
    for (int fn = 0; fn < 2; ++fn) {
      cs[fn] += __shfl_xor(cs[fn], 16);
      cs[fn] += __shfl_xor(cs[fn], 32);
    }
    if (l < 16) {
#pragma unroll
      for (int fn = 0; fn < 2; ++fn)
        atomicAdd(&sumexp[jb + wc * 32 + fn * 16 + l], cs[fn]);
    }
  }
}

// ---- Kernel 4: finalize ---------------------------------------------------
__device__ float block_reduce_256(float v, volatile float* red) {
#pragma unroll
  for (int m = 32; m >= 1; m >>= 1) v += __shfl_xor(v, m);
  __syncthreads();
  if ((threadIdx.x & 63) == 0) red[threadIdx.x >> 6] = v;
  __syncthreads();
  return red[0] + red[1] + red[2] + red[3];
}

__global__ void finalize_kernel(const float* __restrict__ colsum,
                                const float* __restrict__ sumexp,
                                const float* __restrict__ pos,
                                float* __restrict__ out) {
  __shared__ float red[4];
  int t = threadIdx.x;
  float ce = 0.f, t1 = 0.f, t2 = 0.f;
  for (int i = t; i < N_TOT; i += 256) ce += logf(sumexp[i]) - pos[i];
  for (int c = t; c < C_NUM; c += 256) t1 += colsum[c];
  for (int c = t; c < C_NUM; c += 256) t2 += colsum[C_NUM + c];
  ce = block_reduce_256(ce, red);
  t1 = block_reduce_256(t1, red);
  t2 = block_reduce_256(t2, red);
  float e1 = 0.f, e2 = 0.f;
  for (int c = t; c < C_NUM; c += 256) {
    float m = colsum[c] / t1;
    e1 += m * logf(m);
  }
  for (int c = t; c < C_NUM; c += 256) {
    float m = colsum[C_NUM + c] / t2;
    e2 += m * logf(m);
  }
  e1 = block_reduce_256(e1, red);
  e2 = block_reduce_256(e2, red);
  if (t == 0) {
    float reg = logf((float)C_NUM) + e1 + logf((float)C_NUM) + e2;
    out[0] = ce / (float)N_TOT + reg;
  }
}

extern "C" void kernel_launch(void* const* d_in, const int* in_sizes, int n_in,
                              void* d_out, int out_size, void* d_ws, size_t ws_size,
                              hipStream_t stream) {
  const float* prob = (const float*)d_in[0];
  const float* prob_s = (const float*)d_in[1];
  float* out = (float*)d_out;

  char* ws = (char*)d_ws;
  uint8_t* Pn = (uint8_t*)ws;                                   // 16 MB fp8
  float* norm2 = (float*)(ws + (size_t)N_TOT * B_TOT);          // 4096 f32
  float* colsum = norm2 + N_TOT;                                // 4096 f32
  float* sumexp = colsum + N_TOT;                               // 4096 f32
  float* invn = sumexp + N_TOT;                                 // 4096 f32
  float* pos = invn + N_TOT;                                    // 4096 f32

  // zero the atomic accumulators (norm2, colsum, sumexp contiguous)
  hipMemsetAsync(norm2, 0, (size_t)3 * N_TOT * sizeof(float), stream);

  transpose_stats_kernel<<<dim3(64, 64), dim3(64, 4), 0, stream>>>(
      prob, prob_s, colsum, norm2, Pn);
  invnorm_kernel<<<16, 256, 0, stream>>>(norm2, invn);
  simgemm_kernel<<<528, 512, 0, stream>>>(Pn, invn, sumexp, pos);
  finalize_kernel<<<1, 256, 0, stream>>>(colsum, sumexp, pos, out);
}

// Round 8
// 113.018 us; speedup vs baseline: 1.8465x; 1.2459x over previous
//
#include <hip/hip_runtime.h>
#include <hip/hip_fp8.h>
#include <stdint.h>
#include <math.h>

#define C_NUM 2048
#define N_TOT 4096
#define B_TOT 4096
#define KNOWN 1024

typedef __attribute__((ext_vector_type(4))) float f32x4;
typedef __attribute__((ext_vector_type(4))) int i32x4;
typedef __attribute__((ext_vector_type(8))) int i32x8;

__device__ __forceinline__ void gld16(const void* g, void* l) {
  __builtin_amdgcn_global_load_lds(
      (const __attribute__((address_space(1))) void*)g,
      (__attribute__((address_space(3))) void*)l, 16, 0, 0);
}

// ---- Kernel 1: transpose + fp8(e4m3) convert + colsum/norm2 partials -----
// Pn[i][b] = fp8(P[i][b]) UNNORMALIZED (values in [0,1)); exact f32 norms
// are applied in the GEMM epilogue.
__global__ void transpose_stats_kernel(const float* __restrict__ prob,
                                       const float* __restrict__ prob_s,
                                       float* __restrict__ colsum,
                                       float* __restrict__ norm2,
                                       uint8_t* __restrict__ Pn) {
  __shared__ float tile[64][65];
  int tx = threadIdx.x;          // 0..63
  int ty = threadIdx.y;          // 0..3
  int c0 = blockIdx.x * 64;      // class tile (0..4095)
  int b0 = blockIdx.y * 64;      // batch tile
  const float* src = (c0 < C_NUM) ? prob : prob_s;
  int colbase = (c0 & (C_NUM - 1)) + tx;
  float s = 0.f, s2 = 0.f;
#pragma unroll
  for (int r = 0; r < 16; ++r) {
    int b = b0 + r * 4 + ty;
    float v = src[(size_t)b * C_NUM + colbase];
    tile[r * 4 + ty][tx] = v;
    s += v;
    s2 += v * v;
  }
  atomicAdd(&colsum[c0 + tx], s);
  atomicAdd(&norm2[c0 + tx], s2);
  __syncthreads();
#pragma unroll
  for (int r = 0; r < 16; ++r) {
    int i = c0 + r * 4 + ty;
    __hip_fp8_e4m3 q(tile[tx][r * 4 + ty]);
    Pn[(size_t)i * B_TOT + b0 + tx] = q.__x;
  }
}

// ---- Kernel 2: invn[i] = 1/max(||P_i||, eps) ------------------------------
__global__ void invnorm_kernel(const float* __restrict__ norm2,
                               float* __restrict__ invn) {
  int i = blockIdx.x * 256 + threadIdx.x;
  invn[i] = 1.0f / fmaxf(sqrtf(norm2[i]), 1e-8f);
}

// ---- Kernel 3: symmetric fused MX-fp8 GEMM (K=128) + softmax epilogue ----
// Triangular tile pairs (jt >= it), 128x128 tile, 512 threads = 8 waves
// (2x4); per-wave 64x32 output (acc[4][2]); mfma_scale_f32_16x16x128_f8f6f4
// with unit E8M0 scales (0x7F in every byte -> exactly 1.0 whatever opsel).
// BK=128 fp8 bytes -> NT=32 K-steps, 64 KB double-buffered LDS.
// Swizzle: 16B granule g of row r stored at phys granule g^(r&7); applied
// as pre-permuted global source (linear gld_lds dest, rule both-sides) and
// XOR'd ds_read addresses -> 2-way banks (free).
__global__ __launch_bounds__(512) void simgemm_kernel(
    const uint8_t* __restrict__ Pn,
    const float* __restrict__ invn,
    float* __restrict__ sumexp,
    float* __restrict__ pos) {
  __shared__ __align__(16) char lds[65536];  // buf b at b*32768: A +0, B +16384

  const int tid = threadIdx.x;
  const int l = tid & 63;
  const int w = tid >> 6;            // wave 0..7
  const int wr = w >> 2, wc = w & 3; // 2x4 wave grid

  // triangular decode: block t -> (it, jt) with jt >= it, 32x32 tile grid
  int t = blockIdx.x;
  int it = 0, rem = 32;
  while (t >= rem) { t -= rem; ++it; --rem; }
  const int jt = it + t;
  const int ib = it * 128;
  const int jb = jt * 128;
  const bool diag = (it == jt);

  // staging: thread tid covers granule g=tid (rows 0-63) and g=tid+512
  // (rows 64-127) of each 128x128B tile half. row = g>>3, phys gran = g&7,
  // logical gran = phys ^ (row&7) -> pre-permuted global column.
  const int srow = tid >> 3;                 // 0..63
  const int glog = (tid & 7) ^ (srow & 7);
  const char* gA = (const char*)Pn + (size_t)(ib + srow) * B_TOT + glog * 16;
  const char* gB = (const char*)Pn + (size_t)(jb + srow) * B_TOT + glog * 16;
  // +64 rows: (srow+64)&7 == srow&7 -> same glog, source just +64 rows.
  const int ldsOf = tid * 16;

  f32x4 acc[4][2];
#pragma unroll
  for (int a = 0; a < 4; ++a)
#pragma unroll
    for (int b = 0; b < 2; ++b)
      acc[a][b] = (f32x4){0.f, 0.f, 0.f, 0.f};

  // fragment read geometry: rows of 128B; lane holds k-block (l>>4)*32
  // (logical granules lg, lg+1 with lg = (l>>4)*2), phys = lg ^ (l&7)
  // (row&7 == l&7 since wr*64, wc*32, fm*16 are all 0 mod 8... 32,16 mod 8 = 0).
  const int arow = wr * 64 + (l & 15);
  const int brow = wc * 32 + (l & 15);
  const int ph0 = ((((l >> 4) * 2) ^ (l & 7)) * 16);  // even chunk byte off
  // odd chunk = ph0 ^ 16

#define STAGE(buf, koff)                                                  \
  do {                                                                    \
    gld16(gA + (koff), lds + (buf) * 32768 + ldsOf);                      \
    gld16(gA + (size_t)64 * B_TOT + (koff), lds + (buf) * 32768 + 8192 + ldsOf); \
    gld16(gB + (koff), lds + (buf) * 32768 + 16384 + ldsOf);              \
    gld16(gB + (size_t)64 * B_TOT + (koff), lds + (buf) * 32768 + 24576 + ldsOf); \
  } while (0)

  STAGE(0, 0);
  __syncthreads();

  int cur = 0;
  const int NT = B_TOT / 128;   // 32 K-steps (128 fp8 each)
  for (int kt = 0; kt < NT; ++kt) {
    if (kt + 1 < NT) STAGE(cur ^ 1, (kt + 1) * 128);

    const char* Abase = lds + cur * 32768;
    const char* Bbase = Abase + 16384;

    i32x8 af[4], bf[2];
#pragma unroll
    for (int f = 0; f < 4; ++f) {
      const char* p = Abase + (arow + f * 16) * 128;
      i32x4 lo = *(const i32x4*)(p + ph0);
      i32x4 hi = *(const i32x4*)(p + (ph0 ^ 16));
      af[f] = __builtin_shufflevector(lo, hi, 0, 1, 2, 3, 4, 5, 6, 7);
    }
#pragma unroll
    for (int f = 0; f < 2; ++f) {
      const char* p = Bbase + (brow + f * 16) * 128;
      i32x4 lo = *(const i32x4*)(p + ph0);
      i32x4 hi = *(const i32x4*)(p + (ph0 ^ 16));
      bf[f] = __builtin_shufflevector(lo, hi, 0, 1, 2, 3, 4, 5, 6, 7);
    }

#pragma unroll
    for (int fm = 0; fm < 4; ++fm)
#pragma unroll
      for (int fn = 0; fn < 2; ++fn)
        acc[fm][fn] = __builtin_amdgcn_mfma_scale_f32_16x16x128_f8f6f4(
            af[fm], bf[fn], acc[fm][fn], 0, 0,  // cbsz=fp8, blgp=fp8
            0, 0x7F7F7F7F, 0, 0x7F7F7F7F);      // unit scales
    __syncthreads();
    cur ^= 1;
  }
#undef STAGE

  // epilogue. v = 2 * dot * invn[i] * invn[j]
  float invj[2];
#pragma unroll
  for (int fn = 0; fn < 2; ++fn)
    invj[fn] = invn[jb + wc * 32 + fn * 16 + (l & 15)];

  if (diag) {
#pragma unroll
    for (int fm = 0; fm < 4; ++fm) {
#pragma unroll
      for (int r = 0; r < 4; ++r) {
        const int i = ib + wr * 64 + fm * 16 + (l >> 4) * 4 + r;
        const float invi = invn[i];
        float rs = 0.f;
#pragma unroll
        for (int fn = 0; fn < 2; ++fn) {
          const int j = jb + wc * 32 + fn * 16 + (l & 15);
          float v = acc[fm][fn][r] * 2.0f * invi * invj[fn];
          if (j != i)   // i^2048 can't occur inside a diagonal block
            rs += (((i & 1024) == 0) && (j < KNOWN)) ? 1.0f : __expf(v);
        }
        rs += __shfl_xor(rs, 1);
        rs += __shfl_xor(rs, 2);
        rs += __shfl_xor(rs, 4);
        rs += __shfl_xor(rs, 8);
        if ((l & 15) == 0) atomicAdd(&sumexp[i], rs);
      }
    }
  } else {
    float cs[2] = {0.f, 0.f};   // per-fn contribution to column rows j
#pragma unroll
    for (int fm = 0; fm < 4; ++fm) {
#pragma unroll
      for (int r = 0; r < 4; ++r) {
        const int i = ib + wr * 64 + fm * 16 + (l >> 4) * 4 + r;
        const float invi = invn[i];
        float rs = 0.f;
#pragma unroll
        for (int fn = 0; fn < 2; ++fn) {
          const int j = jb + wc * 32 + fn * 16 + (l & 15);
          float v = acc[fm][fn][r] * 2.0f * invi * invj[fn];
          if (j == (i ^ 2048)) {
            pos[i] = v;          // symmetric entry has the same value
            pos[j] = v;
          } else {               // j != i always holds off-diagonal
            float e = __expf(v);
            rs += (((i & 1024) == 0) && (j < KNOWN)) ? 1.0f : e;
            cs[fn] += (((j & 1024) == 0) && (i < KNOWN)) ? 1.0f : e;
          }
        }
        rs += __shfl_xor(rs, 1);
        rs += __shfl_xor(rs, 2);
        rs += __shfl_xor(rs, 4);
        rs += __shfl_xor(rs, 8);
        if ((l & 15) == 0) atomicAdd(&sumexp[i], rs);
      }
    }
#pragma unroll
    for (int fn = 0; fn < 2; ++fn) {
      cs[fn] += __shfl_xor(cs[fn], 16);
      cs[fn] += __shfl_xor(cs[fn], 32);
    }
    if (l < 16) {
#pragma unroll
      for (int fn = 0; fn < 2; ++fn)
        atomicAdd(&sumexp[jb + wc * 32 + fn * 16 + l], cs[fn]);
    }
  }
}

// ---- Kernel 4: finalize ---------------------------------------------------
__device__ float block_reduce_256(float v, volatile float* red) {
#pragma unroll
  for (int m = 32; m >= 1; m >>= 1) v += __shfl_xor(v, m);
  __syncthreads();
  if ((threadIdx.x & 63) == 0) red[threadIdx.x >> 6] = v;
  __syncthreads();
  return red[0] + red[1] + red[2] + red[3];
}

__global__ void finalize_kernel(const float* __restrict__ colsum,
                                const float* __restrict__ sumexp,
                                const float* __restrict__ pos,
                                float* __restrict__ out) {
  __shared__ float red[4];
  int t = threadIdx.x;
  float ce = 0.f, t1 = 0.f, t2 = 0.f;
  for (int i = t; i < N_TOT; i += 256) ce += logf(sumexp[i]) - pos[i];
  for (int c = t; c < C_NUM; c += 256) t1 += colsum[c];
  for (int c = t; c < C_NUM; c += 256) t2 += colsum[C_NUM + c];
  ce = block_reduce_256(ce, red);
  t1 = block_reduce_256(t1, red);
  t2 = block_reduce_256(t2, red);
  float e1 = 0.f, e2 = 0.f;
  for (int c = t; c < C_NUM; c += 256) {
    float m = colsum[c] / t1;
    e1 += m * logf(m);
  }
  for (int c = t; c < C_NUM; c += 256) {
    float m = colsum[C_NUM + c] / t2;
    e2 += m * logf(m);
  }
  e1 = block_reduce_256(e1, red);
  e2 = block_reduce_256(e2, red);
  if (t == 0) {
    float reg = logf((float)C_NUM) + e1 + logf((float)C_NUM) + e2;
    out[0] = ce / (float)N_TOT + reg;
  }
}

extern "C" void kernel_launch(void* const* d_in, const int* in_sizes, int n_in,
                              void* d_out, int out_size, void* d_ws, size_t ws_size,
                              hipStream_t stream) {
  const float* prob = (const float*)d_in[0];
  const float* prob_s = (const float*)d_in[1];
  float* out = (float*)d_out;

  char* ws = (char*)d_ws;
  uint8_t* Pn = (uint8_t*)ws;                                   // 16 MB fp8
  float* norm2 = (float*)(ws + (size_t)N_TOT * B_TOT);          // 4096 f32
  float* colsum = norm2 + N_TOT;                                // 4096 f32
  float* sumexp = colsum + N_TOT;                               // 4096 f32
  float* invn = sumexp + N_TOT;                                 // 4096 f32
  float* pos = invn + N_TOT;                                    // 4096 f32

  // zero the atomic accumulators (norm2, colsum, sumexp contiguous)
  hipMemsetAsync(norm2, 0, (size_t)3 * N_TOT * sizeof(float), stream);

  transpose_stats_kernel<<<dim3(64, 64), dim3(64, 4), 0, stream>>>(
      prob, prob_s, colsum, norm2, Pn);
  invnorm_kernel<<<16, 256, 0, stream>>>(norm2, invn);
  simgemm_kernel<<<528, 512, 0, stream>>>(Pn, invn, sumexp, pos);
  finalize_kernel<<<1, 256, 0, stream>>>(colsum, sumexp, pos, out);
}